// Round 1
// baseline (26430.576 us; speedup 1.0000x reference)
//
#include <hip/hip_runtime.h>
#include <hip/hip_bf16.h>
#include <math.h>

// Problem dims (fixed by the reference)
#define Bb 64
#define Tt 512
#define Ii 1024
#define Hh 2048

// ---------------------------------------------------------------------------
// Kernel 1: x_proj = input @ w_ih^T + b_ih  -> written into outs region of d_out
//   input: [M=B*T][K=I] row-major, w_ih: [N=H][K=I] row-major (k-contiguous both)
//   out:   [M][N]
// Classic LDS-tiled fp32 GEMM: BM=64, BN=64, BK=32, 256 threads, 4x4 per thread.
// ---------------------------------------------------------------------------
__global__ __launch_bounds__(256) void xproj_kernel(
    const float* __restrict__ A,     // input [32768][1024]
    const float* __restrict__ W,     // w_ih  [2048][1024]
    const float* __restrict__ bias,  // b_ih  [2048]
    float* __restrict__ out)         // [32768][2048]
{
    constexpr int BM = 64, BN = 64, BK = 32;
    constexpr int K = Ii, N = Hh;

    __shared__ float As[BK][BM + 4];   // k-major, padded
    __shared__ float Ws[BK][BN + 4];

    const int tid = threadIdx.x;
    const int m0 = blockIdx.y * BM;
    const int n0 = blockIdx.x * BN;
    const int tx = tid & 15;        // 0..15 -> n
    const int ty = tid >> 4;        // 0..15 -> m

    const int lrow = tid >> 3;      // 0..31
    const int lkq  = tid & 7;       // 0..7  -> k4

    float acc[4][4] = {};

    for (int k0 = 0; k0 < K; k0 += BK) {
        // Load A tile (64 rows x 32 k) and W tile (64 rows x 32 k), store k-major.
        #pragma unroll
        for (int p = 0; p < 2; ++p) {
            const int r = p * 32 + lrow;
            float4 va = *(const float4*)(A + (size_t)(m0 + r) * K + k0 + lkq * 4);
            As[lkq * 4 + 0][r] = va.x;
            As[lkq * 4 + 1][r] = va.y;
            As[lkq * 4 + 2][r] = va.z;
            As[lkq * 4 + 3][r] = va.w;
            float4 vw = *(const float4*)(W + (size_t)(n0 + r) * K + k0 + lkq * 4);
            Ws[lkq * 4 + 0][r] = vw.x;
            Ws[lkq * 4 + 1][r] = vw.y;
            Ws[lkq * 4 + 2][r] = vw.z;
            Ws[lkq * 4 + 3][r] = vw.w;
        }
        __syncthreads();

        #pragma unroll
        for (int kk = 0; kk < BK; ++kk) {
            float4 a = *(const float4*)&As[kk][ty * 4];
            float4 w = *(const float4*)&Ws[kk][tx * 4];
            acc[0][0] += a.x * w.x; acc[0][1] += a.x * w.y; acc[0][2] += a.x * w.z; acc[0][3] += a.x * w.w;
            acc[1][0] += a.y * w.x; acc[1][1] += a.y * w.y; acc[1][2] += a.y * w.z; acc[1][3] += a.y * w.w;
            acc[2][0] += a.z * w.x; acc[2][1] += a.z * w.y; acc[2][2] += a.z * w.z; acc[2][3] += a.z * w.w;
            acc[3][0] += a.w * w.x; acc[3][1] += a.w * w.y; acc[3][2] += a.w * w.z; acc[3][3] += a.w * w.w;
        }
        __syncthreads();
    }

    // Epilogue: add bias, write coalesced float4 per row.
    const float4 bj = *(const float4*)(bias + n0 + tx * 4);
    #pragma unroll
    for (int i = 0; i < 4; ++i) {
        const int m = m0 + ty * 4 + i;
        float4 r;
        r.x = acc[i][0] + bj.x;
        r.y = acc[i][1] + bj.y;
        r.z = acc[i][2] + bj.z;
        r.w = acc[i][3] + bj.w;
        *(float4*)(out + (size_t)m * N + n0 + tx * 4) = r;
    }
}

// ---------------------------------------------------------------------------
// Kernel 2: one recurrence step.
//   out[b, t, j] = tanh( xp(=out[b,t,j]) + internal[b,t] + b_hh[j]
//                        + sum_k hprev[b,k] * w_hh[j,k] )
//   hprev row b = (t==0) ? h0[b,:] : out[b, t-1, :]
// Grid: 256 WGs x 256 threads. WG -> 8 columns (j), all 64 batches.
// Wave w handles j = jt*8 + w*2 + {0,1}; lane = batch index b.
// h staged in LDS in 128-k chunks, XOR-swizzled float4 slots so the
// transposed ds_read_b128 (per-lane row) is bank-conflict free.
// ---------------------------------------------------------------------------
__global__ __launch_bounds__(256) void step_kernel(
    const float* __restrict__ w_hh,     // [H][H]
    const float* __restrict__ b_hh,     // [H]
    const float* __restrict__ internal, // [B][T]
    const float* __restrict__ h0,       // [B][H] (h0[0] of [1,B,H])
    float* __restrict__ out,            // [B][T][H] then [B][H] tail
    const int t)
{
    constexpr int KC = 128;              // k-chunk
    __shared__ float Hs[Bb][KC];         // swizzled float4 slots

    const int tid  = threadIdx.x;
    const int lane = tid & 63;           // = batch b for compute
    const int wave = __builtin_amdgcn_readfirstlane(tid >> 6);  // 0..3, wave-uniform SGPR
    const int jt   = blockIdx.x;         // 0..255
    const int j0   = jt * 8 + wave * 2;  // this wave's first column
    const int j1   = j0 + 1;

    const float* __restrict__ w0 = w_hh + (size_t)j0 * Hh;
    const float* __restrict__ w1 = w_hh + (size_t)j1 * Hh;

    const int slot  = tid & 31;          // staging: float4 slot 0..31
    const int brow0 = tid >> 5;          // staging: 0..7

    float acc0 = 0.0f, acc1 = 0.0f;

    for (int c = 0; c < Hh / KC; ++c) {
        // ---- stage h chunk: 64 rows x 128 k, 8 passes of 8 rows ----
        #pragma unroll
        for (int p = 0; p < 8; ++p) {
            const int b = p * 8 + brow0;
            const float* src = (t == 0)
                ? (h0 + (size_t)b * Hh)
                : (out + (size_t)b * Tt * Hh + (size_t)(t - 1) * Hh);
            float4 v = *(const float4*)(src + c * KC + slot * 4);
            const int s2 = slot ^ (b & 7);
            *(float4*)&Hs[b][s2 * 4] = v;
        }
        __syncthreads();

        // ---- compute over this chunk ----
        const float* wc0 = w0 + c * KC;
        const float* wc1 = w1 + c * KC;
        #pragma unroll 8
        for (int k4 = 0; k4 < KC / 4; ++k4) {
            float4 hv  = *(const float4*)&Hs[lane][(k4 ^ (lane & 7)) * 4];
            float4 wv0 = *(const float4*)(wc0 + k4 * 4);
            float4 wv1 = *(const float4*)(wc1 + k4 * 4);
            acc0 += hv.x * wv0.x + hv.y * wv0.y + hv.z * wv0.z + hv.w * wv0.w;
            acc1 += hv.x * wv1.x + hv.y * wv1.y + hv.z * wv1.z + hv.w * wv1.w;
        }
        __syncthreads();
    }

    // ---- epilogue: b = lane, columns j0, j1 ----
    const size_t obase = (size_t)lane * Tt * Hh + (size_t)t * Hh;
    const float xp0 = out[obase + j0];
    const float xp1 = out[obase + j1];
    const float nz  = internal[lane * Tt + t];
    const float g0  = tanhf(xp0 + nz + b_hh[j0] + acc0);
    const float g1  = tanhf(xp1 + nz + b_hh[j1] + acc1);
    out[obase + j0] = g0;
    out[obase + j1] = g1;

    if (t == Tt - 1) {
        float* hl = out + (size_t)Bb * Tt * Hh;   // h_last region [B][H]
        hl[(size_t)lane * Hh + j0] = g0;
        hl[(size_t)lane * Hh + j1] = g1;
    }
}

// ---------------------------------------------------------------------------
extern "C" void kernel_launch(void* const* d_in, const int* in_sizes, int n_in,
                              void* d_out, int out_size, void* d_ws, size_t ws_size,
                              hipStream_t stream) {
    const float* input    = (const float*)d_in[0];  // [B,T,I]
    const float* internal = (const float*)d_in[1];  // [B,T]
    const float* w_ih     = (const float*)d_in[2];  // [H,I]
    const float* w_hh     = (const float*)d_in[3];  // [H,H]
    const float* b_ih     = (const float*)d_in[4];  // [H]
    const float* b_hh     = (const float*)d_in[5];  // [H]
    const float* h0       = (const float*)d_in[6];  // [1,B,H]
    // d_in[7] = trunc (forward no-op)
    float* out = (float*)d_out;                     // [B,T,H] ++ [1,B,H]

    // Stage 1: x_proj (+ b_ih) into the outs region.
    dim3 g1(Hh / 64, (Bb * Tt) / 64);
    hipLaunchKernelGGL(xproj_kernel, g1, dim3(256), 0, stream,
                       input, w_ih, b_ih, out);

    // Stage 2: 512 sequential recurrence steps, in-place over the outs region.
    for (int t = 0; t < Tt; ++t) {
        hipLaunchKernelGGL(step_kernel, dim3(256), dim3(256), 0, stream,
                           w_hh, b_hh, internal, h0, out, t);
    }
}